// Round 9
// baseline (19519.310 us; speedup 1.0000x reference)
//
#include <hip/hip_runtime.h>

#define N4K 4096
#define DFEAT 256
constexpr float P_UNIF = 1.0f / 4096.0f;

typedef __attribute__((ext_vector_type(8))) short bf16x8;
typedef __attribute__((ext_vector_type(4))) float f32x4;

__device__ __forceinline__ float bfl(unsigned u) { return __uint_as_float(u << 16); }
__device__ __forceinline__ float bfh(unsigned u) { return __uint_as_float(u & 0xffff0000u); }
__device__ __forceinline__ unsigned short f2bf(float f) {
  unsigned u = __float_as_uint(f);
  u += 0x7fffu + ((u >> 16) & 1u);   // RNE
  return (unsigned short)(u >> 16);
}
__device__ __forceinline__ void load_lds16(const void* g, void* l) {
  __builtin_amdgcn_global_load_lds(
      (const __attribute__((address_space(1))) void*)g,
      (__attribute__((address_space(3))) void*)l, 16, 0, 0);
}

// ---------------- row-normalize + cast to bf16 -------------------------------
__global__ void k_normalize(const float* __restrict__ in, unsigned short* __restrict__ out) {
  const int wv = threadIdx.x >> 6, lane = threadIdx.x & 63;
  const int row = blockIdx.x * 4 + wv;
  const float4 v = ((const float4*)(in + (size_t)row * DFEAT))[lane];
  float ss = v.x * v.x + v.y * v.y + v.z * v.z + v.w * v.w;
#pragma unroll
  for (int off = 32; off; off >>= 1) ss += __shfl_xor(ss, off);
  const float inv = rsqrtf(ss);
  unsigned a = (unsigned)f2bf(v.x * inv) | ((unsigned)f2bf(v.y * inv) << 16);
  unsigned b = (unsigned)f2bf(v.z * inv) | ((unsigned)f2bf(v.w * inv) << 16);
  ((uint2*)(out + (size_t)row * DFEAT))[lane] = make_uint2(a, b);
}

// ---------------- bf16 transpose [R x C] -> [C x R], 64x64 tiles -------------
__global__ void k_transpose(const unsigned short* __restrict__ in,
                            unsigned short* __restrict__ out, int R, int C) {
  __shared__ unsigned short t[64][65];
  const int tid = threadIdx.x;
  const int tx = tid & 63, ty = tid >> 6;
  const int c0 = blockIdx.x * 64, r0 = blockIdx.y * 64;
#pragma unroll
  for (int k = 0; k < 16; k++) {
    const int r = ty * 16 + k;
    t[r][tx] = in[(size_t)(r0 + r) * C + c0 + tx];
  }
  __syncthreads();
#pragma unroll
  for (int k = 0; k < 16; k++) {
    const int r = ty * 16 + k;
    out[(size_t)(c0 + r) * R + r0 + tx] = t[tx][r];
  }
}

// ---------------- generic zero -----------------------------------------------
__global__ void k_zerof(float* __restrict__ p, int n) {
  const int i = blockIdx.x * 256 + threadIdx.x;
  if (i < n) p[i] = 0.0f;
}

// ---------------- m97-pattern bf16 GEMM: C = A @ B^T -------------------------
// mode 0: bf16 out = acc                       (LDS-staged coalesced store)
// mode 2: bf16 out = exp(sArg*acc - ctE[col])  (LDS-staged coalesced store)
// mode 3: fp32 outf[(z*gridDim.y*128+row)*ldo+col] = acc (LDS-staged)
// mode 4: stats only: colsum/colsumsq -> psum/psq, max(-acc) -> dmx
__global__ __launch_bounds__(256) void k_gemm_bt(
    const unsigned short* __restrict__ A, const unsigned short* __restrict__ B,
    int ld, int kChunk, unsigned short* __restrict__ out, float* __restrict__ outf,
    int ldo, int mode, const float* __restrict__ ctE,
    const float* __restrict__ dm1, const float* __restrict__ dm2,
    float* __restrict__ psum, float* __restrict__ psq, float* __restrict__ dmx)
{
  __shared__ __align__(16) unsigned char SMEM[16384];
  __shared__ float cs[128], cq[128];
  __shared__ float wmx[4];
  unsigned short* Als = (unsigned short*)SMEM;            // 128x32 bf16 = 8 KB
  unsigned short* Bls = (unsigned short*)(SMEM + 8192);   // 128x32 bf16 = 8 KB
  const int tid = threadIdx.x;
  const int w = tid >> 6, lane = tid & 63;
  const int wr = w >> 1, wc = w & 1;                 // 2x2 waves, 64x64 each
  const int mbase = blockIdx.y * 128, nbase = blockIdx.x * 128;
  const int kBase = blockIdx.z * kChunk;

  if (mode == 4 && tid < 128) { cs[tid] = 0.f; cq[tid] = 0.f; }

  const f32x4 fz = {0.f, 0.f, 0.f, 0.f};
  f32x4 acc[4][4];
#pragma unroll
  for (int m = 0; m < 4; m++)
#pragma unroll
    for (int n = 0; n < 4; n++) acc[m][n] = fz;

  const int sRow = lane >> 2;            // 0..15
  const int sCol = (lane & 3) * 8;       // 0,8,16,24
  const unsigned short* gA = A + (size_t)(mbase + w * 32 + sRow) * ld + sCol;
  const unsigned short* gB = B + (size_t)(nbase + w * 32 + sRow) * ld + sCol;
  unsigned short* lA0 = &Als[(w * 2 + 0) * 512];
  unsigned short* lA1 = &Als[(w * 2 + 1) * 512];
  unsigned short* lB0 = &Bls[(w * 2 + 0) * 512];
  unsigned short* lB1 = &Bls[(w * 2 + 1) * 512];

  const int rA = lane & 15, kg = (lane >> 4) * 8;

  for (int k0 = kBase; k0 < kBase + kChunk; k0 += 32) {
    __syncthreads();
    load_lds16(gA + k0, lA0);
    load_lds16(gA + (size_t)16 * ld + k0, lA1);
    load_lds16(gB + k0, lB0);
    load_lds16(gB + (size_t)16 * ld + k0, lB1);
    __syncthreads();
    bf16x8 a[4], b[4];
#pragma unroll
    for (int m = 0; m < 4; m++)
      a[m] = *(const bf16x8*)&Als[(wr * 64 + m * 16 + rA) * 32 + kg];
#pragma unroll
    for (int n = 0; n < 4; n++)
      b[n] = *(const bf16x8*)&Bls[(wc * 64 + n * 16 + rA) * 32 + kg];
#pragma unroll
    for (int m = 0; m < 4; m++)
#pragma unroll
      for (int n = 0; n < 4; n++)
        acc[m][n] = __builtin_amdgcn_mfma_f32_16x16x32_bf16(a[m], b[n], acc[m][n], 0, 0, 0);
  }

  // C/D layout: col = lane&15, row = (lane>>4)*4 + r   [m89-verified]
  if (mode == 4) {
    float mx = -2.0f;
#pragma unroll
    for (int n = 0; n < 4; n++) {
      float sv = 0.f, sq2 = 0.f;
#pragma unroll
      for (int m = 0; m < 4; m++)
#pragma unroll
        for (int r = 0; r < 4; r++) {
          const float val = acc[m][n][r];
          sv += val; sq2 += val * val;
          mx = fmaxf(mx, -val);
        }
      const int lcol = wc * 64 + n * 16 + (lane & 15);
      atomicAdd(&cs[lcol], sv);
      atomicAdd(&cq[lcol], sq2);
    }
#pragma unroll
    for (int off = 32; off; off >>= 1) mx = fmaxf(mx, __shfl_xor(mx, off));
    if (lane == 0) wmx[w] = mx;
    __syncthreads();
    if (tid == 0)
      atomicMax((int*)dmx, __float_as_int(fmaxf(fmaxf(wmx[0], wmx[1]), fmaxf(wmx[2], wmx[3]))));
    if (tid < 128) {
      atomicAdd(&psum[nbase + tid], cs[tid]);
      atomicAdd(&psq[nbase + tid], cq[tid]);
    }
    return;
  }

  const int lrow16 = (lane >> 4) * 4;
  if (mode == 3) {
    float* ef = (float*)SMEM;                     // [32][128] fp32 = 16 KB
    for (int m = 0; m < 4; m++) {
      __syncthreads();
#pragma unroll
      for (int n = 0; n < 4; n++) {
        const int col = wc * 64 + n * 16 + (lane & 15);
#pragma unroll
        for (int r = 0; r < 4; r++)
          ef[(wr * 16 + lrow16 + r) * 128 + col] = acc[m][n][r];
      }
      __syncthreads();
#pragma unroll
      for (int h = 0; h < 4; h++) {
        const int t = tid + h * 256;
        const int cr = t >> 5, cc = (t & 31) * 4;
        const int grow = mbase + (cr >> 4) * 64 + m * 16 + (cr & 15);
        *(uint4*)&outf[((size_t)blockIdx.z * (gridDim.y * 128) + grow) * ldo + nbase + cc]
            = *(uint4*)&ef[cr * 128 + cc];
      }
    }
  } else {
    float sArg = 0.f;
    if (mode == 2) sArg = 40.0f / ((1.0f + *dm1) * (1.0f + *dm2));
    unsigned short* eb = (unsigned short*)SMEM;   // [32][136] bf16 = 8.5 KB
    for (int m = 0; m < 4; m++) {
      __syncthreads();
#pragma unroll
      for (int n = 0; n < 4; n++) {
        const int col = wc * 64 + n * 16 + (lane & 15);
        const float cv = (mode == 2) ? ctE[nbase + col] : 0.0f;
#pragma unroll
        for (int r = 0; r < 4; r++) {
          float val = acc[m][n][r];
          if (mode == 2) val = __expf(fmaf(sArg, val, -cv));
          eb[(wr * 16 + lrow16 + r) * 136 + col] = f2bf(val);
        }
      }
      __syncthreads();
#pragma unroll
      for (int h = 0; h < 2; h++) {
        const int t = tid + h * 256;
        const int cr = t >> 4, cc = (t & 15) * 8;
        const int grow = mbase + (cr >> 4) * 64 + m * 16 + (cr & 15);
        *(uint4*)&out[(size_t)grow * ldo + nbase + cc] = *(uint4*)&eb[cr * 136 + cc];
      }
    }
  }
}

// ctE_j = [ (1-2*g2_j+s2_j)/m2^2 + (2/(m1*m2))*g2_j ] / eps
__global__ void k_ctfinal(const float* __restrict__ psum, const float* __restrict__ psq,
                          const float* __restrict__ dm1p, const float* __restrict__ dm2p,
                          float* __restrict__ ctE) {
  const int j = blockIdx.x * 256 + threadIdx.x;
  const float g2 = psum[j] * (1.0f / N4K);
  const float s2 = psq[j] * (1.0f / N4K);
  const float m1 = 1.0f + *dm1p, m2 = 1.0f + *dm2p;
  ctE[j] = ((1.0f - 2.0f * g2 + s2) / (m2 * m2) + (2.0f / (m1 * m2)) * g2) * 20.0f;
}

// ---------------- it=0: Yt0[d][i] = (1/N^2) * rowsum(X2t[d]) -----------------
__global__ void k_yt0(const unsigned short* __restrict__ X2t, unsigned short* __restrict__ Yt) {
  __shared__ float red[256];
  const int d = blockIdx.x, t = threadIdx.x;
  const unsigned short* row = X2t + (size_t)d * N4K;
  const uint4 q = *(const uint4*)&row[t * 16];
  const uint4 q2 = *(const uint4*)&row[t * 16 + 8];
  float s = bfl(q.x) + bfh(q.x) + bfl(q.y) + bfh(q.y) + bfl(q.z) + bfh(q.z)
          + bfl(q.w) + bfh(q.w) + bfl(q2.x) + bfh(q2.x) + bfl(q2.y) + bfh(q2.y)
          + bfl(q2.z) + bfh(q2.z) + bfl(q2.w) + bfh(q2.w);
  red[t] = s;
  __syncthreads();
  for (int st = 128; st > 0; st >>= 1) {
    if (t < st) red[t] += red[t + st];
    __syncthreads();
  }
  const unsigned short pv = f2bf(red[0] * (P_UNIF * P_UNIF));
  const unsigned pk = (unsigned)pv | ((unsigned)pv << 16);
  uint4* dst = (uint4*)(Yt + (size_t)d * N4K);
  dst[t] = make_uint4(pk, pk, pk, pk);
  dst[t + 256] = make_uint4(pk, pk, pk, pk);
}

// ---------------- X2vt[d][i] = X2t[d][i] * v[i] ------------------------------
__global__ void k_x2v(const unsigned short* __restrict__ X2t, const float* __restrict__ v,
                      unsigned short* __restrict__ X2vt) {
  const int d = blockIdx.x, t = threadIdx.x;
  const int i0 = t * 16;
  const unsigned short* src = X2t + (size_t)d * N4K + i0;
  unsigned short* dst = X2vt + (size_t)d * N4K + i0;
  const uint4 a = *(const uint4*)src;
  const uint4 b = *(const uint4*)(src + 8);
  const float4 v0 = *(const float4*)&v[i0];
  const float4 v1 = *(const float4*)&v[i0 + 4];
  const float4 v2 = *(const float4*)&v[i0 + 8];
  const float4 v3 = *(const float4*)&v[i0 + 12];
  unsigned r0 = (unsigned)f2bf(bfl(a.x) * v0.x) | ((unsigned)f2bf(bfh(a.x) * v0.y) << 16);
  unsigned r1 = (unsigned)f2bf(bfl(a.y) * v0.z) | ((unsigned)f2bf(bfh(a.y) * v0.w) << 16);
  unsigned r2 = (unsigned)f2bf(bfl(a.z) * v1.x) | ((unsigned)f2bf(bfh(a.z) * v1.y) << 16);
  unsigned r3 = (unsigned)f2bf(bfl(a.w) * v1.z) | ((unsigned)f2bf(bfh(a.w) * v1.w) << 16);
  unsigned r4 = (unsigned)f2bf(bfl(b.x) * v2.x) | ((unsigned)f2bf(bfh(b.x) * v2.y) << 16);
  unsigned r5 = (unsigned)f2bf(bfl(b.y) * v2.z) | ((unsigned)f2bf(bfh(b.y) * v2.w) << 16);
  unsigned r6 = (unsigned)f2bf(bfl(b.z) * v3.x) | ((unsigned)f2bf(bfh(b.z) * v3.y) << 16);
  unsigned r7 = (unsigned)f2bf(bfl(b.w) * v3.z) | ((unsigned)f2bf(bfh(b.w) * v3.w) << 16);
  *(uint4*)dst = make_uint4(r0, r1, r2, r3);
  *(uint4*)(dst + 8) = make_uint4(r4, r5, r6, r7);
}

// ---------------- reduce 4 K-chunk partials of Y, apply u, transpose ---------
__global__ void k_redY(const float* __restrict__ Yp, const float* __restrict__ u,
                       unsigned short* __restrict__ Yt) {
  __shared__ float t[64][65];
  const int tid = threadIdx.x;
  const int tx = tid & 63, ty = tid >> 6;
  const int r0 = blockIdx.x * 64, c0 = blockIdx.y * 64;
#pragma unroll
  for (int k = 0; k < 16; k++) {
    const int r = ty * 16 + k;
    const size_t off = (size_t)(r0 + r) * 256 + c0 + tx;
    float s = 0.f;
#pragma unroll
    for (int z = 0; z < 4; z++) s += Yp[(size_t)z * (N4K * 256) + off];
    t[r][tx] = s;
  }
  __syncthreads();
  const float uu = u[r0 + tx];
#pragma unroll
  for (int k = 0; k < 16; k++) {
    const int r = ty * 16 + k;
    Yt[(size_t)(c0 + r) * N4K + r0 + tx] = f2bf(t[tx][r] * uu);
  }
}

// ---------------- reduce 16 K-chunk partials of PT ---------------------------
__global__ void k_redPT(const float* __restrict__ Pp, unsigned short* __restrict__ PTb) {
  const int idx = blockIdx.x * 256 + threadIdx.x;
  float s = 0.f;
#pragma unroll
  for (int z = 0; z < 16; z++) s += Pp[z * 65536 + idx];
  PTb[idx] = f2bf(s);
}

// ---------------- device-wide barrier (flat counter + generation) ------------
__device__ __forceinline__ void gbar(int* cnt, int* gen, int target) {
  __threadfence();
  __syncthreads();
  if (threadIdx.x == 0) {
    const int v = __hip_atomic_fetch_add(cnt, 1, __ATOMIC_ACQ_REL, __HIP_MEMORY_SCOPE_AGENT);
    if (v == 255) {
      __hip_atomic_store(cnt, 0, __ATOMIC_RELAXED, __HIP_MEMORY_SCOPE_AGENT);
      __hip_atomic_fetch_add(gen, 1, __ATOMIC_RELEASE, __HIP_MEMORY_SCOPE_AGENT);
    } else {
      while (__hip_atomic_load(gen, __ATOMIC_ACQUIRE, __HIP_MEMORY_SCOPE_AGENT) < target)
        __builtin_amdgcn_s_sleep(2);
    }
  }
  __syncthreads();
  __threadfence();
}

// ---------------- persistent Sinkhorn: 20 iterations, K in LDS ---------------
// 256 blocks x 512 thr (cooperative). Block b owns rows [16b,16b+16).
__global__ __launch_bounds__(512, 1) void k_sinkP(
    const unsigned short* __restrict__ Km, float* __restrict__ u,
    float* __restrict__ v, float* __restrict__ partials,
    int* cnt, int* gen, int genBase)
{
  __shared__ unsigned short Kl[16 * N4K];   // 128 KiB
  __shared__ float vs[N4K];                 // 16 KiB
  __shared__ float us[16];
  const int tid = threadIdx.x;
  const int wv = tid >> 6, lane = tid & 63;
  const int row0 = blockIdx.x * 16;
  // stage 16 rows once: wave wv loads rows 2wv, 2wv+1 (16 x 1KB chunks)
  {
    const unsigned short* g = Km + (size_t)(row0 + wv * 2) * N4K + lane * 8;
    unsigned short* l = &Kl[wv * 2 * N4K];
#pragma unroll
    for (int i = 0; i < 16; i++)
      load_lds16(g + i * 512, l + i * 512);
  }
  for (int i = tid; i < N4K; i += 512) vs[i] = 1.0f;
  __syncthreads();

  int bt = genBase;
  for (int s = 0; s < 20; s++) {
    // phase A: u = p/(K v) for rows 2wv, 2wv+1 (LDS)
    {
      const unsigned short* rA = &Kl[(wv * 2) * N4K];
      const unsigned short* rB = rA + N4K;
      float accA = 0.f, accB = 0.f;
#pragma unroll
      for (int p = 0; p < 8; p++) {
        const int j0 = p * 512 + lane * 8;
        const uint4 qa = *(const uint4*)&rA[j0];
        const uint4 qb = *(const uint4*)&rB[j0];
        const float4 xa = *(const float4*)&vs[j0];
        const float4 xb = *(const float4*)&vs[j0 + 4];
        accA += bfl(qa.x) * xa.x + bfh(qa.x) * xa.y + bfl(qa.y) * xa.z + bfh(qa.y) * xa.w
              + bfl(qa.z) * xb.x + bfh(qa.z) * xb.y + bfl(qa.w) * xb.z + bfh(qa.w) * xb.w;
        accB += bfl(qb.x) * xa.x + bfh(qb.x) * xa.y + bfl(qb.y) * xa.z + bfh(qb.y) * xa.w
              + bfl(qb.z) * xb.x + bfh(qb.z) * xb.y + bfl(qb.w) * xb.z + bfh(qb.w) * xb.w;
      }
#pragma unroll
      for (int off = 32; off; off >>= 1) {
        accA += __shfl_xor(accA, off);
        accB += __shfl_xor(accB, off);
      }
      if (lane == 0) {
        us[wv * 2] = P_UNIF / accA;
        us[wv * 2 + 1] = P_UNIF / accB;
      }
    }
    __syncthreads();
    // phase B: partial colsums of K^T u (8 cols/thread, LDS reads)
    {
      const int c0 = tid * 8;
      float a0 = 0, a1 = 0, a2 = 0, a3 = 0, a4 = 0, a5 = 0, a6 = 0, a7 = 0;
#pragma unroll
      for (int r = 0; r < 16; r++) {
        const float ur = us[r];
        const uint4 q = *(const uint4*)&Kl[r * N4K + c0];
        a0 += ur * bfl(q.x); a1 += ur * bfh(q.x);
        a2 += ur * bfl(q.y); a3 += ur * bfh(q.y);
        a4 += ur * bfl(q.z); a5 += ur * bfh(q.z);
        a6 += ur * bfl(q.w); a7 += ur * bfh(q.w);
      }
      float* pp = partials + (size_t)blockIdx.x * N4K + c0;
      *(float4*)pp = make_float4(a0, a1, a2, a3);
      *(float4*)(pp + 4) = make_float4(a4, a5, a6, a7);
    }
    gbar(cnt, gen, ++bt);
    // phase C: reduce own 16 columns across all 256 blocks; v = q/sum
    {
      const int cl = tid >> 5, g = tid & 31;
      const int col = row0 + cl;
      float sum = 0.f;
#pragma unroll
      for (int k = 0; k < 8; k++)
        sum += partials[(size_t)(g + 32 * k) * N4K + col];
#pragma unroll
      for (int off = 16; off; off >>= 1) sum += __shfl_xor(sum, off);
      if (g == 0) v[col] = P_UNIF / sum;
    }
    if (s < 19) {
      gbar(cnt, gen, ++bt);
      for (int i = tid; i < N4K; i += 512) vs[i] = v[i];
      __syncthreads();
    }
  }
  if (tid < 16) u[row0 + tid] = us[tid];
}

// ---------------- loss = -sum log(u_i K_ii v_i + 1e-10) ----------------------
__global__ void k_loss(const unsigned short* __restrict__ K, const float* __restrict__ u,
                       const float* __restrict__ v, float* __restrict__ out) {
  const int tid = threadIdx.x;
  float acc = 0.f;
  for (int i = tid; i < N4K; i += 256) {
    const float d = u[i] * bfl((unsigned)K[(size_t)i * (N4K + 1)]) * v[i];
    acc += logf(d + 1e-10f);
  }
  __shared__ float red[256];
  red[tid] = acc;
  __syncthreads();
  for (int st = 128; st > 0; st >>= 1) {
    if (tid < st) red[tid] += red[tid + st];
    __syncthreads();
  }
  if (tid == 0) out[0] = -red[0];
}

// ============================================================================
extern "C" void kernel_launch(void* const* d_in, const int* in_sizes, int n_in,
                              void* d_out, int out_size, void* d_ws, size_t ws_size,
                              hipStream_t stream) {
  const float* f1 = (const float*)d_in[0];
  const float* f2 = (const float*)d_in[1];
  float* out = (float*)d_out;

  char* w = (char*)d_ws;
  const size_t NN = (size_t)N4K * N4K;
  unsigned short* X1 = (unsigned short*)w;   w += (size_t)N4K * DFEAT * 2;
  unsigned short* X2 = (unsigned short*)w;   w += (size_t)N4K * DFEAT * 2;
  unsigned short* X1t = (unsigned short*)w;  w += (size_t)N4K * DFEAT * 2;
  unsigned short* X2t = (unsigned short*)w;  w += (size_t)N4K * DFEAT * 2;
  unsigned short* X2vt = (unsigned short*)w; w += (size_t)N4K * DFEAT * 2;
  unsigned short* Zb = (unsigned short*)w;   w += (size_t)N4K * DFEAT * 2;
  unsigned short* Yt = (unsigned short*)w;   w += (size_t)N4K * DFEAT * 2;
  unsigned short* PTb = (unsigned short*)w;  w += (size_t)DFEAT * DFEAT * 2;
  unsigned short* KA = (unsigned short*)w;   w += NN * 2;
  unsigned short* KB = (unsigned short*)w;   w += NN * 2;
  float* Yp = (float*)w;    w += (size_t)4 * N4K * DFEAT * 4;    // 16 MB
  float* Pp = (float*)w;    w += (size_t)16 * DFEAT * DFEAT * 4; // 4 MB
  float* spart = (float*)w; w += (size_t)256 * N4K * 4;          // 4 MB
  float* stats = (float*)w; w += (size_t)17024 * 4;
  float* uvec = (float*)w;  w += N4K * 4;
  float* vvec = (float*)w;  w += N4K * 4;
  float* ctE = (float*)w;   w += N4K * 4;

  float* psum2 = stats;
  float* psq2 = stats + 4096;
  float* psumD = stats + 8192;
  float* psqD = stats + 12288;
  float* dmax1 = stats + 16384;
  float* dmax2 = stats + 16385;
  int* barCnt = (int*)(stats + 16640);   // own cacheline
  int* barGen = (int*)(stats + 16672);   // own cacheline

  const dim3 b256(256);

  k_normalize<<<1024, b256, 0, stream>>>(f1, X1);
  k_normalize<<<1024, b256, 0, stream>>>(f2, X2);
  k_transpose<<<dim3(4, 64), b256, 0, stream>>>(X1, X1t, N4K, DFEAT);
  k_transpose<<<dim3(4, 64), b256, 0, stream>>>(X2, X2t, N4K, DFEAT);
  k_zerof<<<67, b256, 0, stream>>>(stats, 17024);   // stats + barrier flags

  // Gram stats (mode 4): G1 -> dmax1; G2 -> colsums + dmax2
  k_gemm_bt<<<dim3(32, 32, 1), b256, 0, stream>>>(X1, X1, DFEAT, DFEAT, nullptr, nullptr,
                                                  0, 4, nullptr, nullptr, nullptr,
                                                  psumD, psqD, dmax1);
  k_gemm_bt<<<dim3(32, 32, 1), b256, 0, stream>>>(X2, X2, DFEAT, DFEAT, nullptr, nullptr,
                                                  0, 4, nullptr, nullptr, nullptr,
                                                  psum2, psq2, dmax2);
  k_ctfinal<<<16, b256, 0, stream>>>(psum2, psq2, dmax1, dmax2, ctE);

  unsigned short* Kprev = nullptr;
  for (int it = 0; it < 5; it++) {
    if (it == 0) {
      k_yt0<<<256, b256, 0, stream>>>(X2t, Yt);
    } else {
      k_x2v<<<256, b256, 0, stream>>>(X2t, vvec, X2vt);
      k_gemm_bt<<<dim3(2, 32, 4), b256, 0, stream>>>(Kprev, X2vt, N4K, 1024, nullptr, Yp,
                                                     DFEAT, 3, nullptr, nullptr, nullptr,
                                                     nullptr, nullptr, nullptr);
      k_redY<<<dim3(64, 4), b256, 0, stream>>>(Yp, uvec, Yt);
    }
    // PT = Y^T X1 (K-split 16)
    k_gemm_bt<<<dim3(2, 2, 16), b256, 0, stream>>>(Yt, X1t, N4K, 256, nullptr, Pp,
                                                   DFEAT, 3, nullptr, nullptr, nullptr,
                                                   nullptr, nullptr, nullptr);
    k_redPT<<<256, b256, 0, stream>>>(Pp, PTb);
    // Z = X1 P
    k_gemm_bt<<<dim3(2, 32, 1), b256, 0, stream>>>(X1, PTb, DFEAT, DFEAT, Zb, nullptr,
                                                   DFEAT, 0, nullptr, nullptr, nullptr,
                                                   nullptr, nullptr, nullptr);
    // K = exp(sArg * Z X2^T - ctE_j)
    unsigned short* Knew = (Kprev == KA) ? KB : KA;
    k_gemm_bt<<<dim3(32, 32, 1), b256, 0, stream>>>(Zb, X2, DFEAT, DFEAT, Knew, nullptr,
                                                    N4K, 2, ctE, dmax1, dmax2,
                                                    nullptr, nullptr, nullptr);
    // 20 Sinkhorn iterations, persistent (39 barriers; gen accumulates)
    {
      int genBase = it * 39;
      void* kargs[] = {(void*)&Knew, (void*)&uvec, (void*)&vvec, (void*)&spart,
                       (void*)&barCnt, (void*)&barGen, (void*)&genBase};
      hipLaunchCooperativeKernel((const void*)k_sinkP, dim3(256), dim3(512),
                                 kargs, 0, stream);
    }
    Kprev = Knew;
  }
  k_loss<<<1, b256, 0, stream>>>(Kprev, uvec, vvec, out);
}

// Round 10
// 1561.312 us; speedup vs baseline: 12.5019x; 12.5019x over previous
//
#include <hip/hip_runtime.h>

#define N4K 4096
#define DFEAT 256
constexpr float P_UNIF = 1.0f / 4096.0f;

typedef __attribute__((ext_vector_type(8))) short bf16x8;
typedef __attribute__((ext_vector_type(4))) float f32x4;

__device__ __forceinline__ float bfl(unsigned u) { return __uint_as_float(u << 16); }
__device__ __forceinline__ float bfh(unsigned u) { return __uint_as_float(u & 0xffff0000u); }
__device__ __forceinline__ unsigned short f2bf(float f) {
  unsigned u = __float_as_uint(f);
  u += 0x7fffu + ((u >> 16) & 1u);   // RNE
  return (unsigned short)(u >> 16);
}
// f32 (>=0) -> OCP e4m3fn byte, RNE. Verified: 0.5->48, 1.0->56, 448->126.
__device__ __forceinline__ unsigned char f2fp8(float v) {
  v = fminf(v, 448.0f);
  if (v < 0.015625f) return (unsigned char)__float2uint_rn(v * 512.0f);  // denormal
  unsigned u = __float_as_uint(v);
  u += 0x7FFFFu + ((u >> 20) & 1u);
  return (unsigned char)(((u >> 20) & 0x7FF) - 960);
}
__device__ __forceinline__ void load_lds16(const void* g, void* l) {
  __builtin_amdgcn_global_load_lds(
      (const __attribute__((address_space(1))) void*)g,
      (__attribute__((address_space(3))) void*)l, 16, 0, 0);
}

#if __has_builtin(__builtin_amdgcn_cvt_pk_f32_fp8)
#define FP8_HW 1
#else
#define FP8_HW 0
#endif

// ---------------- row-normalize + cast to bf16 -------------------------------
__global__ void k_normalize(const float* __restrict__ in, unsigned short* __restrict__ out) {
  const int wv = threadIdx.x >> 6, lane = threadIdx.x & 63;
  const int row = blockIdx.x * 4 + wv;
  const float4 v = ((const float4*)(in + (size_t)row * DFEAT))[lane];
  float ss = v.x * v.x + v.y * v.y + v.z * v.z + v.w * v.w;
#pragma unroll
  for (int off = 32; off; off >>= 1) ss += __shfl_xor(ss, off);
  const float inv = rsqrtf(ss);
  unsigned a = (unsigned)f2bf(v.x * inv) | ((unsigned)f2bf(v.y * inv) << 16);
  unsigned b = (unsigned)f2bf(v.z * inv) | ((unsigned)f2bf(v.w * inv) << 16);
  ((uint2*)(out + (size_t)row * DFEAT))[lane] = make_uint2(a, b);
}

// ---------------- bf16 transpose [R x C] -> [C x R], 64x64 tiles -------------
__global__ void k_transpose(const unsigned short* __restrict__ in,
                            unsigned short* __restrict__ out, int R, int C) {
  __shared__ unsigned short t[64][65];
  const int tid = threadIdx.x;
  const int tx = tid & 63, ty = tid >> 6;
  const int c0 = blockIdx.x * 64, r0 = blockIdx.y * 64;
#pragma unroll
  for (int k = 0; k < 16; k++) {
    const int r = ty * 16 + k;
    t[r][tx] = in[(size_t)(r0 + r) * C + c0 + tx];
  }
  __syncthreads();
#pragma unroll
  for (int k = 0; k < 16; k++) {
    const int r = ty * 16 + k;
    out[(size_t)(c0 + r) * R + r0 + tx] = t[tx][r];
  }
}

// ---------------- generic zero -----------------------------------------------
__global__ void k_zerof(float* __restrict__ p, int n) {
  const int i = blockIdx.x * 256 + threadIdx.x;
  if (i < n) p[i] = 0.0f;
}

// ---------------- m97-pattern bf16 GEMM: C = A @ B^T -------------------------
// mode 0: bf16 out = acc                       (LDS-staged coalesced store)
// mode 2: bf16 out = exp(sArg*acc - ctE[col] - shift), PLUS fp8 copy to K8
// mode 3: fp32 outf[(z*gridDim.y*128+row)*ldo+col] = acc (LDS-staged)
// mode 4: stats only: colsum/colsumsq -> psum/psq, max(-acc) -> dmx
__global__ __launch_bounds__(256) void k_gemm_bt(
    const unsigned short* __restrict__ A, const unsigned short* __restrict__ B,
    int ld, int kChunk, unsigned short* __restrict__ out, float* __restrict__ outf,
    int ldo, int mode, const float* __restrict__ ctE,
    const float* __restrict__ dm1, const float* __restrict__ dm2,
    float* __restrict__ psum, float* __restrict__ psq, float* __restrict__ dmx,
    unsigned char* __restrict__ K8, const float* __restrict__ shiftp)
{
  __shared__ __align__(16) unsigned char SMEM[16384];
  __shared__ float cs[128], cq[128];
  __shared__ float wmx[4];
  unsigned short* Als = (unsigned short*)SMEM;            // 128x32 bf16 = 8 KB
  unsigned short* Bls = (unsigned short*)(SMEM + 8192);   // 128x32 bf16 = 8 KB
  const int tid = threadIdx.x;
  const int w = tid >> 6, lane = tid & 63;
  const int wr = w >> 1, wc = w & 1;                 // 2x2 waves, 64x64 each
  const int mbase = blockIdx.y * 128, nbase = blockIdx.x * 128;
  const int kBase = blockIdx.z * kChunk;

  if (mode == 4 && tid < 128) { cs[tid] = 0.f; cq[tid] = 0.f; }

  const f32x4 fz = {0.f, 0.f, 0.f, 0.f};
  f32x4 acc[4][4];
#pragma unroll
  for (int m = 0; m < 4; m++)
#pragma unroll
    for (int n = 0; n < 4; n++) acc[m][n] = fz;

  const int sRow = lane >> 2;            // 0..15
  const int sCol = (lane & 3) * 8;       // 0,8,16,24
  const unsigned short* gA = A + (size_t)(mbase + w * 32 + sRow) * ld + sCol;
  const unsigned short* gB = B + (size_t)(nbase + w * 32 + sRow) * ld + sCol;
  unsigned short* lA0 = &Als[(w * 2 + 0) * 512];
  unsigned short* lA1 = &Als[(w * 2 + 1) * 512];
  unsigned short* lB0 = &Bls[(w * 2 + 0) * 512];
  unsigned short* lB1 = &Bls[(w * 2 + 1) * 512];

  const int rA = lane & 15, kg = (lane >> 4) * 8;

  for (int k0 = kBase; k0 < kBase + kChunk; k0 += 32) {
    __syncthreads();
    load_lds16(gA + k0, lA0);
    load_lds16(gA + (size_t)16 * ld + k0, lA1);
    load_lds16(gB + k0, lB0);
    load_lds16(gB + (size_t)16 * ld + k0, lB1);
    __syncthreads();
    bf16x8 a[4], b[4];
#pragma unroll
    for (int m = 0; m < 4; m++)
      a[m] = *(const bf16x8*)&Als[(wr * 64 + m * 16 + rA) * 32 + kg];
#pragma unroll
    for (int n = 0; n < 4; n++)
      b[n] = *(const bf16x8*)&Bls[(wc * 64 + n * 16 + rA) * 32 + kg];
#pragma unroll
    for (int m = 0; m < 4; m++)
#pragma unroll
      for (int n = 0; n < 4; n++)
        acc[m][n] = __builtin_amdgcn_mfma_f32_16x16x32_bf16(a[m], b[n], acc[m][n], 0, 0, 0);
  }

  // C/D layout: col = lane&15, row = (lane>>4)*4 + r   [m89-verified]
  if (mode == 4) {
    float mx = -2.0f;
#pragma unroll
    for (int n = 0; n < 4; n++) {
      float sv = 0.f, sq2 = 0.f;
#pragma unroll
      for (int m = 0; m < 4; m++)
#pragma unroll
        for (int r = 0; r < 4; r++) {
          const float val = acc[m][n][r];
          sv += val; sq2 += val * val;
          mx = fmaxf(mx, -val);
        }
      const int lcol = wc * 64 + n * 16 + (lane & 15);
      atomicAdd(&cs[lcol], sv);
      atomicAdd(&cq[lcol], sq2);
    }
#pragma unroll
    for (int off = 32; off; off >>= 1) mx = fmaxf(mx, __shfl_xor(mx, off));
    if (lane == 0) wmx[w] = mx;
    __syncthreads();
    if (tid == 0)
      atomicMax((int*)dmx, __float_as_int(fmaxf(fmaxf(wmx[0], wmx[1]), fmaxf(wmx[2], wmx[3]))));
    if (tid < 128) {
      atomicAdd(&psum[nbase + tid], cs[tid]);
      atomicAdd(&psq[nbase + tid], cq[tid]);
    }
    return;
  }

  const int lrow16 = (lane >> 4) * 4;
  if (mode == 3) {
    float* ef = (float*)SMEM;                     // [32][128] fp32 = 16 KB
    for (int m = 0; m < 4; m++) {
      __syncthreads();
#pragma unroll
      for (int n = 0; n < 4; n++) {
        const int col = wc * 64 + n * 16 + (lane & 15);
#pragma unroll
        for (int r = 0; r < 4; r++)
          ef[(wr * 16 + lrow16 + r) * 128 + col] = acc[m][n][r];
      }
      __syncthreads();
#pragma unroll
      for (int h = 0; h < 4; h++) {
        const int t = tid + h * 256;
        const int cr = t >> 5, cc = (t & 31) * 4;
        const int grow = mbase + (cr >> 4) * 64 + m * 16 + (cr & 15);
        *(uint4*)&outf[((size_t)blockIdx.z * (gridDim.y * 128) + grow) * ldo + nbase + cc]
            = *(uint4*)&ef[cr * 128 + cc];
      }
    }
  } else if (mode == 2) {
    const float sArg = 40.0f / ((1.0f + *dm1) * (1.0f + *dm2));
    const float sh = *shiftp;
    unsigned short* eb = (unsigned short*)SMEM;               // [32][136] bf16 = 8704 B
    unsigned char* eb8 = (unsigned char*)(SMEM + 8704);       // [32][144] u8 = 4608 B
    for (int m = 0; m < 4; m++) {
      __syncthreads();
#pragma unroll
      for (int n = 0; n < 4; n++) {
        const int col = wc * 64 + n * 16 + (lane & 15);
        const float cv = ctE[nbase + col] + sh;
#pragma unroll
        for (int r = 0; r < 4; r++) {
          const float val = __expf(fmaf(sArg, acc[m][n][r], -cv));
          eb[(wr * 16 + lrow16 + r) * 136 + col] = f2bf(val);
          eb8[(wr * 16 + lrow16 + r) * 144 + col] = f2fp8(val);
        }
      }
      __syncthreads();
#pragma unroll
      for (int h = 0; h < 2; h++) {
        const int t = tid + h * 256;
        const int cr = t >> 4, cc = (t & 15) * 8;
        const int grow = mbase + (cr >> 4) * 64 + m * 16 + (cr & 15);
        *(uint4*)&out[(size_t)grow * ldo + nbase + cc] = *(uint4*)&eb[cr * 136 + cc];
      }
      {
        const int cr = tid >> 3, cc = (tid & 7) * 16;
        const int grow = mbase + (cr >> 4) * 64 + m * 16 + (cr & 15);
        *(uint4*)&K8[(size_t)grow * N4K + nbase + cc] = *(uint4*)&eb8[cr * 144 + cc];
      }
    }
  } else {
    unsigned short* eb = (unsigned short*)SMEM;   // [32][136] bf16
    for (int m = 0; m < 4; m++) {
      __syncthreads();
#pragma unroll
      for (int n = 0; n < 4; n++) {
        const int col = wc * 64 + n * 16 + (lane & 15);
#pragma unroll
        for (int r = 0; r < 4; r++)
          eb[(wr * 16 + lrow16 + r) * 136 + col] = f2bf(acc[m][n][r]);
      }
      __syncthreads();
#pragma unroll
      for (int h = 0; h < 2; h++) {
        const int t = tid + h * 256;
        const int cr = t >> 4, cc = (t & 15) * 8;
        const int grow = mbase + (cr >> 4) * 64 + m * 16 + (cr & 15);
        *(uint4*)&out[(size_t)grow * ldo + nbase + cc] = *(uint4*)&eb[cr * 136 + cc];
      }
    }
  }
}

// ctE_j = [ (1-2*g2_j+s2_j)/m2^2 + (2/(m1*m2))*g2_j ] / eps ; also sum(ctE)
__global__ void k_ctfinal(const float* __restrict__ psum, const float* __restrict__ psq,
                          const float* __restrict__ dm1p, const float* __restrict__ dm2p,
                          float* __restrict__ ctE, float* __restrict__ ctsum) {
  __shared__ float red[256];
  const int tid = threadIdx.x;
  const int j = blockIdx.x * 256 + tid;
  const float g2 = psum[j] * (1.0f / N4K);
  const float s2 = psq[j] * (1.0f / N4K);
  const float m1 = 1.0f + *dm1p, m2 = 1.0f + *dm2p;
  const float v = ((1.0f - 2.0f * g2 + s2) / (m2 * m2) + (2.0f / (m1 * m2)) * g2) * 20.0f;
  ctE[j] = v;
  red[tid] = v;
  __syncthreads();
  for (int st = 128; st > 0; st >>= 1) {
    if (tid < st) red[tid] += red[tid + st];
    __syncthreads();
  }
  if (tid == 0) atomicAdd(ctsum, red[0]);
}

// ---------------- it=0: Yt0[d][i] = (1/N^2) * rowsum(X2t[d]); also x2sum -----
__global__ void k_yt0(const unsigned short* __restrict__ X2t, unsigned short* __restrict__ Yt,
                      float* __restrict__ x2sum) {
  __shared__ float red[256];
  const int d = blockIdx.x, t = threadIdx.x;
  const unsigned short* row = X2t + (size_t)d * N4K;
  const uint4 q = *(const uint4*)&row[t * 16];
  const uint4 q2 = *(const uint4*)&row[t * 16 + 8];
  float s = bfl(q.x) + bfh(q.x) + bfl(q.y) + bfh(q.y) + bfl(q.z) + bfh(q.z)
          + bfl(q.w) + bfh(q.w) + bfl(q2.x) + bfh(q2.x) + bfl(q2.y) + bfh(q2.y)
          + bfl(q2.z) + bfh(q2.z) + bfl(q2.w) + bfh(q2.w);
  red[t] = s;
  __syncthreads();
  for (int st = 128; st > 0; st >>= 1) {
    if (t < st) red[t] += red[t + st];
    __syncthreads();
  }
  if (t == 0) x2sum[d] = red[0];
  const unsigned short pv = f2bf(red[0] * (P_UNIF * P_UNIF));
  const unsigned pk = (unsigned)pv | ((unsigned)pv << 16);
  uint4* dst = (uint4*)(Yt + (size_t)d * N4K);
  dst[t] = make_uint4(pk, pk, pk, pk);
  dst[t + 256] = make_uint4(pk, pk, pk, pk);
}

// ---------------- X2vt[d][i] = X2t[d][i] * v[i] ------------------------------
__global__ void k_x2v(const unsigned short* __restrict__ X2t, const float* __restrict__ v,
                      unsigned short* __restrict__ X2vt) {
  const int d = blockIdx.x, t = threadIdx.x;
  const int i0 = t * 16;
  const unsigned short* src = X2t + (size_t)d * N4K + i0;
  unsigned short* dst = X2vt + (size_t)d * N4K + i0;
  const uint4 a = *(const uint4*)src;
  const uint4 b = *(const uint4*)(src + 8);
  const float4 v0 = *(const float4*)&v[i0];
  const float4 v1 = *(const float4*)&v[i0 + 4];
  const float4 v2 = *(const float4*)&v[i0 + 8];
  const float4 v3 = *(const float4*)&v[i0 + 12];
  unsigned r0 = (unsigned)f2bf(bfl(a.x) * v0.x) | ((unsigned)f2bf(bfh(a.x) * v0.y) << 16);
  unsigned r1 = (unsigned)f2bf(bfl(a.y) * v0.z) | ((unsigned)f2bf(bfh(a.y) * v0.w) << 16);
  unsigned r2 = (unsigned)f2bf(bfl(a.z) * v1.x) | ((unsigned)f2bf(bfh(a.z) * v1.y) << 16);
  unsigned r3 = (unsigned)f2bf(bfl(a.w) * v1.z) | ((unsigned)f2bf(bfh(a.w) * v1.w) << 16);
  unsigned r4 = (unsigned)f2bf(bfl(b.x) * v2.x) | ((unsigned)f2bf(bfh(b.x) * v2.y) << 16);
  unsigned r5 = (unsigned)f2bf(bfl(b.y) * v2.z) | ((unsigned)f2bf(bfh(b.y) * v2.w) << 16);
  unsigned r6 = (unsigned)f2bf(bfl(b.z) * v3.x) | ((unsigned)f2bf(bfh(b.z) * v3.y) << 16);
  unsigned r7 = (unsigned)f2bf(bfl(b.w) * v3.z) | ((unsigned)f2bf(bfh(b.w) * v3.w) << 16);
  *(uint4*)dst = make_uint4(r0, r1, r2, r3);
  *(uint4*)(dst + 8) = make_uint4(r4, r5, r6, r7);
}

// ---------------- reduce 4 K-chunk partials of Y, apply u, transpose ---------
__global__ void k_redY(const float* __restrict__ Yp, const float* __restrict__ u,
                       unsigned short* __restrict__ Yt) {
  __shared__ float t[64][65];
  const int tid = threadIdx.x;
  const int tx = tid & 63, ty = tid >> 6;
  const int r0 = blockIdx.x * 64, c0 = blockIdx.y * 64;
#pragma unroll
  for (int k = 0; k < 16; k++) {
    const int r = ty * 16 + k;
    const size_t off = (size_t)(r0 + r) * 256 + c0 + tx;
    float s = 0.f;
#pragma unroll
    for (int z = 0; z < 4; z++) s += Yp[(size_t)z * (N4K * 256) + off];
    t[r][tx] = s;
  }
  __syncthreads();
  const float uu = u[r0 + tx];
#pragma unroll
  for (int k = 0; k < 16; k++) {
    const int r = ty * 16 + k;
    Yt[(size_t)(c0 + r) * N4K + r0 + tx] = f2bf(t[tx][r] * uu);
  }
}

// ---------------- reduce 16 K-chunk partials of PT ---------------------------
__global__ void k_redPT(const float* __restrict__ Pp, unsigned short* __restrict__ PTb) {
  const int idx = blockIdx.x * 256 + threadIdx.x;
  float s = 0.f;
#pragma unroll
  for (int z = 0; z < 16; z++) s += Pp[z * 65536 + idx];
  PTb[idx] = f2bf(s);
}

// ---------------- Zb column sums (partial, 64 blocks) ------------------------
__global__ void k_zcol(const unsigned short* __restrict__ Zb, float* __restrict__ zpart) {
  const int c = threadIdx.x;
  const int r0 = blockIdx.x * 64;
  float s = 0.f;
  for (int r = 0; r < 64; r++)
    s += bfl((unsigned)Zb[(size_t)(r0 + r) * 256 + c]);
  zpart[blockIdx.x * 256 + c] = s;
}

// shift = sArg * mean(Z X2^T) - mean(ctE), via rank-1 identity
__global__ void k_shift(const float* __restrict__ zpart, const float* __restrict__ x2sum,
                        const float* __restrict__ ctsum, const float* __restrict__ dm1,
                        const float* __restrict__ dm2, float* __restrict__ shift) {
  __shared__ float red[256];
  const int c = threadIdx.x;
  float zc = 0.f;
#pragma unroll
  for (int b = 0; b < 64; b++) zc += zpart[b * 256 + c];
  red[c] = zc * x2sum[c];
  __syncthreads();
  for (int st = 128; st > 0; st >>= 1) {
    if (c < st) red[c] += red[c + st];
    __syncthreads();
  }
  if (c == 0) {
    const float meanacc = red[0] * (1.0f / (16777216.0f));
    const float sArg = 40.0f / ((1.0f + *dm1) * (1.0f + *dm2));
    shift[0] = sArg * meanacc - ctsum[0] * (1.0f / N4K);
  }
}

// ---------------- fp8 Sinkhorn iteration (K8 L2-resident, no staging) --------
// 256 blocks x 512 thr; block b owns rows [16b,16b+16).
__global__ __launch_bounds__(512) void k_sink8(
    const unsigned char* __restrict__ K8, const float* __restrict__ vin,
    float* __restrict__ u, float* __restrict__ partials, int first, int last)
{
  __shared__ float vs[N4K];     // 16 KiB
  __shared__ float lut[256];
  __shared__ float us[16];
  const int tid = threadIdx.x;
  if (tid < 256) {
    const int e = (tid >> 3) & 15, m = tid & 7;
    lut[tid] = e ? ldexpf((float)(8 + m), e - 10) : ldexpf((float)m, -9);
  }
  if (first) {
    for (int i = tid; i < N4K; i += 512) vs[i] = 1.0f;
  } else {
    float4* vl = (float4*)vs;
    const float4* vg = (const float4*)vin;
    vl[tid] = vg[tid];
    vl[tid + 512] = vg[tid + 512];
  }
  __syncthreads();
  const int wv = tid >> 6, lane = tid & 63;
  const int row0 = blockIdx.x * 16;

#if FP8_HW
#define DEC4(W, J, ACC) { \
    auto _lo = __builtin_amdgcn_cvt_pk_f32_fp8((int)(W), false); \
    auto _hi = __builtin_amdgcn_cvt_pk_f32_fp8((int)(W), true);  \
    ACC += _lo[0] * vs[(J)] + _lo[1] * vs[(J) + 1] + _hi[0] * vs[(J) + 2] + _hi[1] * vs[(J) + 3]; }
#else
#define DEC4(W, J, ACC) { \
    ACC += lut[(W) & 255] * vs[(J)] + lut[((W) >> 8) & 255] * vs[(J) + 1] \
         + lut[((W) >> 16) & 255] * vs[(J) + 2] + lut[(W) >> 24] * vs[(J) + 3]; }
#endif

  // phase A: u = p/(K v) for rows 2wv, 2wv+1
  {
    const uint4* rA = (const uint4*)(K8 + (size_t)(row0 + wv * 2) * N4K);
    const uint4* rB = (const uint4*)(K8 + (size_t)(row0 + wv * 2 + 1) * N4K);
    float accA = 0.f, accB = 0.f;
#pragma unroll
    for (int p = 0; p < 4; p++) {
      const int j0 = p * 1024 + lane * 16;
      const uint4 qa = rA[p * 64 + lane];
      const uint4 qb = rB[p * 64 + lane];
      DEC4(qa.x, j0, accA); DEC4(qa.y, j0 + 4, accA);
      DEC4(qa.z, j0 + 8, accA); DEC4(qa.w, j0 + 12, accA);
      DEC4(qb.x, j0, accB); DEC4(qb.y, j0 + 4, accB);
      DEC4(qb.z, j0 + 8, accB); DEC4(qb.w, j0 + 12, accB);
    }
#pragma unroll
    for (int off = 32; off; off >>= 1) {
      accA += __shfl_xor(accA, off);
      accB += __shfl_xor(accB, off);
    }
    if (lane == 0) {
      us[wv * 2] = P_UNIF / accA;
      us[wv * 2 + 1] = P_UNIF / accB;
    }
  }
  __syncthreads();
  float uu[16];
#pragma unroll
  for (int r = 0; r < 16; r++) uu[r] = us[r];
  // phase B: partial colsums of K^T u (8 cols/thread)
  {
    const int c0 = tid * 8;
    const unsigned char* base = K8 + (size_t)row0 * N4K + c0;
    float a0 = 0, a1 = 0, a2 = 0, a3 = 0, a4 = 0, a5 = 0, a6 = 0, a7 = 0;
#pragma unroll
    for (int r = 0; r < 16; r++) {
      const uint2 q = *(const uint2*)(base + (size_t)r * N4K);
      const float ur = uu[r];
#if FP8_HW
      auto l0 = __builtin_amdgcn_cvt_pk_f32_fp8((int)q.x, false);
      auto h0 = __builtin_amdgcn_cvt_pk_f32_fp8((int)q.x, true);
      auto l1 = __builtin_amdgcn_cvt_pk_f32_fp8((int)q.y, false);
      auto h1 = __builtin_amdgcn_cvt_pk_f32_fp8((int)q.y, true);
      a0 += ur * l0[0]; a1 += ur * l0[1]; a2 += ur * h0[0]; a3 += ur * h0[1];
      a4 += ur * l1[0]; a5 += ur * l1[1]; a6 += ur * h1[0]; a7 += ur * h1[1];
#else
      a0 += ur * lut[q.x & 255]; a1 += ur * lut[(q.x >> 8) & 255];
      a2 += ur * lut[(q.x >> 16) & 255]; a3 += ur * lut[q.x >> 24];
      a4 += ur * lut[q.y & 255]; a5 += ur * lut[(q.y >> 8) & 255];
      a6 += ur * lut[(q.y >> 16) & 255]; a7 += ur * lut[q.y >> 24];
#endif
    }
    float* pp = partials + (size_t)blockIdx.x * N4K + c0;
    *(float4*)pp = make_float4(a0, a1, a2, a3);
    *(float4*)(pp + 4) = make_float4(a4, a5, a6, a7);
  }
  if (last && tid < 16) u[row0 + tid] = us[tid];
}

// v_j = q / sum_{b<256} partials[b][j].  grid 128 x 256; block covers 32 cols.
__global__ void k_sinkfin(const float* __restrict__ partials, float* __restrict__ v) {
  __shared__ float red[8][32];
  const int tid = threadIdx.x;
  const int c = (blockIdx.x << 5) + (tid & 31);
  const int s = tid >> 5;                     // 0..7
  float acc = 0.f;
  const float* p = partials + (size_t)s * 32 * N4K + c;
#pragma unroll 8
  for (int b = 0; b < 32; b++) acc += p[(size_t)b * N4K];
  red[s][tid & 31] = acc;
  __syncthreads();
  if (s == 0) {
    float t = red[0][tid] + red[1][tid] + red[2][tid] + red[3][tid]
            + red[4][tid] + red[5][tid] + red[6][tid] + red[7][tid];
    v[c] = P_UNIF / t;
  }
}

// ---------------- loss = -sum log(u_i K_ii v_i + 1e-10) ----------------------
__global__ void k_loss(const unsigned short* __restrict__ K, const float* __restrict__ u,
                       const float* __restrict__ v, float* __restrict__ out) {
  const int tid = threadIdx.x;
  float acc = 0.f;
  for (int i = tid; i < N4K; i += 256) {
    const float d = u[i] * bfl((unsigned)K[(size_t)i * (N4K + 1)]) * v[i];
    acc += logf(d + 1e-10f);
  }
  __shared__ float red[256];
  red[tid] = acc;
  __syncthreads();
  for (int st = 128; st > 0; st >>= 1) {
    if (tid < st) red[tid] += red[tid + st];
    __syncthreads();
  }
  if (tid == 0) out[0] = -red[0];
}

// ============================================================================
extern "C" void kernel_launch(void* const* d_in, const int* in_sizes, int n_in,
                              void* d_out, int out_size, void* d_ws, size_t ws_size,
                              hipStream_t stream) {
  const float* f1 = (const float*)d_in[0];
  const float* f2 = (const float*)d_in[1];
  float* out = (float*)d_out;

  char* w = (char*)d_ws;
  const size_t NN = (size_t)N4K * N4K;
  unsigned short* X1 = (unsigned short*)w;   w += (size_t)N4K * DFEAT * 2;
  unsigned short* X2 = (unsigned short*)w;   w += (size_t)N4K * DFEAT * 2;
  unsigned short* X1t = (unsigned short*)w;  w += (size_t)N4K * DFEAT * 2;
  unsigned short* X2t = (unsigned short*)w;  w += (size_t)N4K * DFEAT * 2;
  unsigned short* X2vt = (unsigned short*)w; w += (size_t)N4K * DFEAT * 2;
  unsigned short* Zb = (unsigned short*)w;   w += (size_t)N4K * DFEAT * 2;
  unsigned short* Yt = (unsigned short*)w;   w += (size_t)N4K * DFEAT * 2;
  unsigned short* PTb = (unsigned short*)w;  w += (size_t)DFEAT * DFEAT * 2;
  unsigned short* KA = (unsigned short*)w;   w += NN * 2;
  unsigned short* KB = (unsigned short*)w;   w += NN * 2;
  unsigned char* K8 = (unsigned char*)w;     w += NN;        // fp8 K, 16.8 MB
  float* Yp = (float*)w;    w += (size_t)4 * N4K * DFEAT * 4;    // 16 MB
  float* Pp = (float*)w;    w += (size_t)16 * DFEAT * DFEAT * 4; // 4 MB
  float* spart = (float*)w; w += (size_t)256 * N4K * 4;          // 4 MB
  float* zpart = (float*)w; w += (size_t)64 * 256 * 4;
  float* stats = (float*)w; w += (size_t)16704 * 4;
  float* uvec = (float*)w;  w += N4K * 4;
  float* vvec = (float*)w;  w += N4K * 4;
  float* ctE = (float*)w;   w += N4K * 4;
  float* x2sum = (float*)w; w += 256 * 4;

  float* psum2 = stats;
  float* psq2 = stats + 4096;
  float* psumD = stats + 8192;
  float* psqD = stats + 12288;
  float* dmax1 = stats + 16384;
  float* dmax2 = stats + 16385;
  float* ctsum = stats + 16386;
  float* shiftv = stats + 16387;

  const dim3 b256(256);

  k_normalize<<<1024, b256, 0, stream>>>(f1, X1);
  k_normalize<<<1024, b256, 0, stream>>>(f2, X2);
  k_transpose<<<dim3(4, 64), b256, 0, stream>>>(X1, X1t, N4K, DFEAT);
  k_transpose<<<dim3(4, 64), b256, 0, stream>>>(X2, X2t, N4K, DFEAT);
  k_zerof<<<66, b256, 0, stream>>>(stats, 16704);

  // Gram stats (mode 4): G1 -> dmax1; G2 -> colsums + dmax2
  k_gemm_bt<<<dim3(32, 32, 1), b256, 0, stream>>>(X1, X1, DFEAT, DFEAT, nullptr, nullptr,
                                                  0, 4, nullptr, nullptr, nullptr,
                                                  psumD, psqD, dmax1, nullptr, nullptr);
  k_gemm_bt<<<dim3(32, 32, 1), b256, 0, stream>>>(X2, X2, DFEAT, DFEAT, nullptr, nullptr,
                                                  0, 4, nullptr, nullptr, nullptr,
                                                  psum2, psq2, dmax2, nullptr, nullptr);
  k_ctfinal<<<16, b256, 0, stream>>>(psum2, psq2, dmax1, dmax2, ctE, ctsum);

  unsigned short* Kprev = nullptr;
  for (int it = 0; it < 5; it++) {
    if (it == 0) {
      k_yt0<<<256, b256, 0, stream>>>(X2t, Yt, x2sum);
    } else {
      k_x2v<<<256, b256, 0, stream>>>(X2t, vvec, X2vt);
      k_gemm_bt<<<dim3(2, 32, 4), b256, 0, stream>>>(Kprev, X2vt, N4K, 1024, nullptr, Yp,
                                                     DFEAT, 3, nullptr, nullptr, nullptr,
                                                     nullptr, nullptr, nullptr, nullptr, nullptr);
      k_redY<<<dim3(64, 4), b256, 0, stream>>>(Yp, uvec, Yt);
    }
    // PT = Y^T X1 (K-split 16)
    k_gemm_bt<<<dim3(2, 2, 16), b256, 0, stream>>>(Yt, X1t, N4K, 256, nullptr, Pp,
                                                   DFEAT, 3, nullptr, nullptr, nullptr,
                                                   nullptr, nullptr, nullptr, nullptr, nullptr);
    k_redPT<<<256, b256, 0, stream>>>(Pp, PTb);
    // Z = X1 P
    k_gemm_bt<<<dim3(2, 32, 1), b256, 0, stream>>>(X1, PTb, DFEAT, DFEAT, Zb, nullptr,
                                                   DFEAT, 0, nullptr, nullptr, nullptr,
                                                   nullptr, nullptr, nullptr, nullptr, nullptr);
    // shift = sArg*mean(Z X2^T) - mean(ctE)   (fp8 range centering)
    k_zcol<<<64, b256, 0, stream>>>(Zb, zpart);
    k_shift<<<1, b256, 0, stream>>>(zpart, x2sum, ctsum, dmax1, dmax2, shiftv);
    // K = exp(sArg * Z X2^T - ctE_j - shift), bf16 + fp8 copies
    unsigned short* Knew = (Kprev == KA) ? KB : KA;
    k_gemm_bt<<<dim3(32, 32, 1), b256, 0, stream>>>(Zb, X2, DFEAT, DFEAT, Knew, nullptr,
                                                    N4K, 2, ctE, dmax1, dmax2,
                                                    nullptr, nullptr, nullptr, K8, shiftv);
    // Sinkhorn: 20 x { u = p/(K v) ; v = q/(K^T u) }, v0 = 1, on fp8 K
    for (int s = 0; s < 20; s++) {
      k_sink8<<<256, dim3(512), 0, stream>>>(K8, vvec, uvec, spart,
                                             s == 0 ? 1 : 0, s == 19 ? 1 : 0);
      k_sinkfin<<<128, b256, 0, stream>>>(spart, vvec);
    }
    Kprev = Knew;
  }
  k_loss<<<1, b256, 0, stream>>>(Kprev, uvec, vvec, out);
}

// Round 11
// 1551.326 us; speedup vs baseline: 12.5823x; 1.0064x over previous
//
#include <hip/hip_runtime.h>

#define N4K 4096
#define DFEAT 256
constexpr float P_UNIF = 1.0f / 4096.0f;

typedef __attribute__((ext_vector_type(8))) short bf16x8;
typedef __attribute__((ext_vector_type(4))) float f32x4;

__device__ __forceinline__ float bfl(unsigned u) { return __uint_as_float(u << 16); }
__device__ __forceinline__ float bfh(unsigned u) { return __uint_as_float(u & 0xffff0000u); }
__device__ __forceinline__ unsigned short f2bf(float f) {
  unsigned u = __float_as_uint(f);
  u += 0x7fffu + ((u >> 16) & 1u);   // RNE
  return (unsigned short)(u >> 16);
}
// f32 (>=0) -> OCP e4m3fn byte, RNE. Verified: 0.5->48, 1.0->56, 448->126.
__device__ __forceinline__ unsigned f2fp8(float v) {
  v = fminf(v, 448.0f);
  if (v < 0.015625f) return __float2uint_rn(v * 512.0f);  // denormal
  unsigned u = __float_as_uint(v);
  u += 0x7FFFFu + ((u >> 20) & 1u);
  return ((u >> 20) & 0x7FF) - 960;
}
// signed variant
__device__ __forceinline__ unsigned f2fp8s(float v) {
  const unsigned s = (__float_as_uint(v) >> 24) & 0x80u;
  return s | f2fp8(fabsf(v));
}
__device__ __forceinline__ float fp8dec(unsigned b) {
  const int e = (b >> 3) & 15, m = b & 7;
  return e ? ldexpf((float)(8 + m), e - 10) : ldexpf((float)m, -9);
}
__device__ __forceinline__ void load_lds16(const void* g, void* l) {
  __builtin_amdgcn_global_load_lds(
      (const __attribute__((address_space(1))) void*)g,
      (__attribute__((address_space(3))) void*)l, 16, 0, 0);
}

#if __has_builtin(__builtin_amdgcn_cvt_pk_f32_fp8)
#define FP8_HW 1
#else
#define FP8_HW 0
#endif

// ---------------- row-normalize + cast to bf16 -------------------------------
__global__ void k_normalize(const float* __restrict__ in, unsigned short* __restrict__ out) {
  const int wv = threadIdx.x >> 6, lane = threadIdx.x & 63;
  const int row = blockIdx.x * 4 + wv;
  const float4 v = ((const float4*)(in + (size_t)row * DFEAT))[lane];
  float ss = v.x * v.x + v.y * v.y + v.z * v.z + v.w * v.w;
#pragma unroll
  for (int off = 32; off; off >>= 1) ss += __shfl_xor(ss, off);
  const float inv = rsqrtf(ss);
  unsigned a = (unsigned)f2bf(v.x * inv) | ((unsigned)f2bf(v.y * inv) << 16);
  unsigned b = (unsigned)f2bf(v.z * inv) | ((unsigned)f2bf(v.w * inv) << 16);
  ((uint2*)(out + (size_t)row * DFEAT))[lane] = make_uint2(a, b);
}

// ---------------- bf16 transpose [R x C] -> [C x R], 64x64 tiles -------------
__global__ void k_transpose(const unsigned short* __restrict__ in,
                            unsigned short* __restrict__ out, int R, int C) {
  __shared__ unsigned short t[64][65];
  const int tid = threadIdx.x;
  const int tx = tid & 63, ty = tid >> 6;
  const int c0 = blockIdx.x * 64, r0 = blockIdx.y * 64;
#pragma unroll
  for (int k = 0; k < 16; k++) {
    const int r = ty * 16 + k;
    t[r][tx] = in[(size_t)(r0 + r) * C + c0 + tx];
  }
  __syncthreads();
#pragma unroll
  for (int k = 0; k < 16; k++) {
    const int r = ty * 16 + k;
    out[(size_t)(c0 + r) * R + r0 + tx] = t[tx][r];
  }
}

// ---------------- generic zero -----------------------------------------------
__global__ void k_zerof(float* __restrict__ p, int n) {
  const int i = blockIdx.x * 256 + threadIdx.x;
  if (i < n) p[i] = 0.0f;
}

// ---------------- row sums of Xt [256][4096] -> s256 -------------------------
__global__ void k_rsum(const unsigned short* __restrict__ Xt, float* __restrict__ s256) {
  __shared__ float red[256];
  const int d = blockIdx.x, t = threadIdx.x;
  const unsigned short* row = Xt + (size_t)d * N4K;
  const uint4 q = *(const uint4*)&row[t * 16];
  const uint4 q2 = *(const uint4*)&row[t * 16 + 8];
  float s = bfl(q.x) + bfh(q.x) + bfl(q.y) + bfh(q.y) + bfl(q.z) + bfh(q.z)
          + bfl(q.w) + bfh(q.w) + bfl(q2.x) + bfh(q2.x) + bfl(q2.y) + bfh(q2.y)
          + bfl(q2.z) + bfh(q2.z) + bfl(q2.w) + bfh(q2.w);
  red[t] = s;
  __syncthreads();
  for (int st = 128; st > 0; st >>= 1) {
    if (t < st) red[t] += red[t + st];
    __syncthreads();
  }
  if (t == 0) s256[d] = red[0];
}

// ---------------- unified GEMM: C = A @ B^T ----------------------------------
// mode 0: bf16 out = acc                       (LDS-staged coalesced store)
// mode 2: fp8 K8 = exp(sArg*acc - ctE[col] - shift)   (fp8 only)
// mode 3: fp32 outf[(z*gridDim.y*128+row)*ldo+col] = acc  (K-split partials)
// mode 4: stats only: colsum/colsumsq -> psum/psq, max(-acc) -> dmx
// mode 5: fp8 A/B operands (A,B reinterpreted as fp8, ld in bytes), mode-3 output
__global__ __launch_bounds__(256) void k_gemm_bt(
    const unsigned short* __restrict__ A, const unsigned short* __restrict__ B,
    int ld, int kChunk, unsigned short* __restrict__ out, float* __restrict__ outf,
    int ldo, int mode, const float* __restrict__ ctE,
    const float* __restrict__ dm1, const float* __restrict__ dm2,
    float* __restrict__ psum, float* __restrict__ psq, float* __restrict__ dmx,
    unsigned char* __restrict__ K8, const float* __restrict__ shiftp)
{
  __shared__ __align__(16) unsigned char SMEM[16384];
  __shared__ float cs[128], cq[128];
  __shared__ float wmx[4];
  const int tid = threadIdx.x;
  const int w = tid >> 6, lane = tid & 63;
  const int wr = w >> 1, wc = w & 1;                 // 2x2 waves, 64x64 each
  const int mbase = blockIdx.y * 128, nbase = blockIdx.x * 128;
  const int kBase = blockIdx.z * kChunk;

  if (mode == 4 && tid < 128) { cs[tid] = 0.f; cq[tid] = 0.f; }

  const f32x4 fz = {0.f, 0.f, 0.f, 0.f};
  f32x4 acc[4][4];
#pragma unroll
  for (int m = 0; m < 4; m++)
#pragma unroll
    for (int n = 0; n < 4; n++) acc[m][n] = fz;

  const int rA = lane & 15;

  if (mode == 5) {
    // fp8 operand path: rows of 32 bytes (K=32 per step)
    const unsigned char* A8 = (const unsigned char*)A;
    const unsigned char* B8 = (const unsigned char*)B;
    unsigned char* As8 = SMEM;                 // 128x32 = 4 KB
    unsigned char* Bs8 = SMEM + 4096;          // 128x32 = 4 KB
    const unsigned char* gA8 = A8 + (size_t)(mbase + w * 32 + (lane >> 1)) * ld + (lane & 1) * 16;
    const unsigned char* gB8 = B8 + (size_t)(nbase + w * 32 + (lane >> 1)) * ld + (lane & 1) * 16;
    unsigned char* lA8 = As8 + w * 1024;
    unsigned char* lB8 = Bs8 + w * 1024;
    const int kg8 = (lane >> 4) * 8;
    for (int k0 = kBase; k0 < kBase + kChunk; k0 += 32) {
      __syncthreads();
      load_lds16(gA8 + k0, lA8);
      load_lds16(gB8 + k0, lB8);
      __syncthreads();
      long a8[4], b8[4];
#pragma unroll
      for (int m = 0; m < 4; m++)
        a8[m] = *(const long*)&As8[(wr * 64 + m * 16 + rA) * 32 + kg8];
#pragma unroll
      for (int n = 0; n < 4; n++)
        b8[n] = *(const long*)&Bs8[(wc * 64 + n * 16 + rA) * 32 + kg8];
#pragma unroll
      for (int m = 0; m < 4; m++)
#pragma unroll
        for (int n = 0; n < 4; n++)
          acc[m][n] = __builtin_amdgcn_mfma_f32_16x16x32_fp8_fp8(a8[m], b8[n], acc[m][n], 0, 0, 0);
    }
  } else {
    unsigned short* Als = (unsigned short*)SMEM;            // 128x32 bf16 = 8 KB
    unsigned short* Bls = (unsigned short*)(SMEM + 8192);   // 128x32 bf16 = 8 KB
    const int sRow = lane >> 2;            // 0..15
    const int sCol = (lane & 3) * 8;       // 0,8,16,24
    const unsigned short* gA = A + (size_t)(mbase + w * 32 + sRow) * ld + sCol;
    const unsigned short* gB = B + (size_t)(nbase + w * 32 + sRow) * ld + sCol;
    unsigned short* lA0 = &Als[(w * 2 + 0) * 512];
    unsigned short* lA1 = &Als[(w * 2 + 1) * 512];
    unsigned short* lB0 = &Bls[(w * 2 + 0) * 512];
    unsigned short* lB1 = &Bls[(w * 2 + 1) * 512];
    const int kg = (lane >> 4) * 8;
    for (int k0 = kBase; k0 < kBase + kChunk; k0 += 32) {
      __syncthreads();
      load_lds16(gA + k0, lA0);
      load_lds16(gA + (size_t)16 * ld + k0, lA1);
      load_lds16(gB + k0, lB0);
      load_lds16(gB + (size_t)16 * ld + k0, lB1);
      __syncthreads();
      bf16x8 a[4], b[4];
#pragma unroll
      for (int m = 0; m < 4; m++)
        a[m] = *(const bf16x8*)&Als[(wr * 64 + m * 16 + rA) * 32 + kg];
#pragma unroll
      for (int n = 0; n < 4; n++)
        b[n] = *(const bf16x8*)&Bls[(wc * 64 + n * 16 + rA) * 32 + kg];
#pragma unroll
      for (int m = 0; m < 4; m++)
#pragma unroll
        for (int n = 0; n < 4; n++)
          acc[m][n] = __builtin_amdgcn_mfma_f32_16x16x32_bf16(a[m], b[n], acc[m][n], 0, 0, 0);
    }
  }

  // C/D layout: col = lane&15, row = (lane>>4)*4 + r   [m89-verified]
  if (mode == 4) {
    float mx = -2.0f;
#pragma unroll
    for (int n = 0; n < 4; n++) {
      float sv = 0.f, sq2 = 0.f;
#pragma unroll
      for (int m = 0; m < 4; m++)
#pragma unroll
        for (int r = 0; r < 4; r++) {
          const float val = acc[m][n][r];
          sv += val; sq2 += val * val;
          mx = fmaxf(mx, -val);
        }
      const int lcol = wc * 64 + n * 16 + (lane & 15);
      atomicAdd(&cs[lcol], sv);
      atomicAdd(&cq[lcol], sq2);
    }
#pragma unroll
    for (int off = 32; off; off >>= 1) mx = fmaxf(mx, __shfl_xor(mx, off));
    if (lane == 0) wmx[w] = mx;
    __syncthreads();
    if (tid == 0)
      atomicMax((int*)dmx, __float_as_int(fmaxf(fmaxf(wmx[0], wmx[1]), fmaxf(wmx[2], wmx[3]))));
    if (tid < 128) {
      atomicAdd(&psum[nbase + tid], cs[tid]);
      atomicAdd(&psq[nbase + tid], cq[tid]);
    }
    return;
  }

  const int lrow16 = (lane >> 4) * 4;
  if (mode == 3 || mode == 5) {
    float* ef = (float*)SMEM;                     // [32][128] fp32 = 16 KB
    for (int m = 0; m < 4; m++) {
      __syncthreads();
#pragma unroll
      for (int n = 0; n < 4; n++) {
        const int col = wc * 64 + n * 16 + (lane & 15);
#pragma unroll
        for (int r = 0; r < 4; r++)
          ef[(wr * 16 + lrow16 + r) * 128 + col] = acc[m][n][r];
      }
      __syncthreads();
#pragma unroll
      for (int h = 0; h < 4; h++) {
        const int t = tid + h * 256;
        const int cr = t >> 5, cc = (t & 31) * 4;
        const int grow = mbase + (cr >> 4) * 64 + m * 16 + (cr & 15);
        *(uint4*)&outf[((size_t)blockIdx.z * (gridDim.y * 128) + grow) * ldo + nbase + cc]
            = *(uint4*)&ef[cr * 128 + cc];
      }
    }
  } else if (mode == 2) {
    const float sArg = 40.0f / ((1.0f + *dm1) * (1.0f + *dm2));
    const float sh = *shiftp;
    unsigned char* eb8 = SMEM;                    // [32][144] u8 = 4608 B
    for (int m = 0; m < 4; m++) {
      __syncthreads();
#pragma unroll
      for (int n = 0; n < 4; n++) {
        const int col = wc * 64 + n * 16 + (lane & 15);
        const float cv = ctE[nbase + col] + sh;
#pragma unroll
        for (int r = 0; r < 4; r++) {
          const float val = __expf(fmaf(sArg, acc[m][n][r], -cv));
          eb8[(wr * 16 + lrow16 + r) * 144 + col] = (unsigned char)f2fp8(val);
        }
      }
      __syncthreads();
      {
        const int cr = tid >> 3, cc = (tid & 7) * 16;
        const int grow = mbase + (cr >> 4) * 64 + m * 16 + (cr & 15);
        *(uint4*)&K8[(size_t)grow * N4K + nbase + cc] = *(uint4*)&eb8[cr * 144 + cc];
      }
    }
  } else {
    unsigned short* eb = (unsigned short*)SMEM;   // [32][136] bf16
    for (int m = 0; m < 4; m++) {
      __syncthreads();
#pragma unroll
      for (int n = 0; n < 4; n++) {
        const int col = wc * 64 + n * 16 + (lane & 15);
#pragma unroll
        for (int r = 0; r < 4; r++)
          eb[(wr * 16 + lrow16 + r) * 136 + col] = f2bf(acc[m][n][r]);
      }
      __syncthreads();
#pragma unroll
      for (int h = 0; h < 2; h++) {
        const int t = tid + h * 256;
        const int cr = t >> 4, cc = (t & 15) * 8;
        const int grow = mbase + (cr >> 4) * 64 + m * 16 + (cr & 15);
        *(uint4*)&out[(size_t)grow * ldo + nbase + cc] = *(uint4*)&eb[cr * 136 + cc];
      }
    }
  }
}

// ctE_j = [ (1-2*g2_j+s2_j)/m2^2 + (2/(m1*m2))*g2_j ] / eps ; also sum(ctE)
__global__ void k_ctfinal(const float* __restrict__ psum, const float* __restrict__ psq,
                          const float* __restrict__ dm1p, const float* __restrict__ dm2p,
                          float* __restrict__ ctE, float* __restrict__ ctsum) {
  __shared__ float red[256];
  const int tid = threadIdx.x;
  const int j = blockIdx.x * 256 + tid;
  const float g2 = psum[j] * (1.0f / N4K);
  const float s2 = psq[j] * (1.0f / N4K);
  const float m1 = 1.0f + *dm1p, m2 = 1.0f + *dm2p;
  const float v = ((1.0f - 2.0f * g2 + s2) / (m2 * m2) + (2.0f / (m1 * m2)) * g2) * 20.0f;
  ctE[j] = v;
  red[tid] = v;
  __syncthreads();
  for (int st = 128; st > 0; st >>= 1) {
    if (tid < st) red[tid] += red[tid + st];
    __syncthreads();
  }
  if (tid == 0) atomicAdd(ctsum, red[0]);
}

// ---------------- it=0: Yt0[d][i] = (1/N^2) * rowsum(X2t[d]); also x2sum -----
__global__ void k_yt0(const unsigned short* __restrict__ X2t, unsigned short* __restrict__ Yt,
                      float* __restrict__ x2sum) {
  __shared__ float red[256];
  const int d = blockIdx.x, t = threadIdx.x;
  const unsigned short* row = X2t + (size_t)d * N4K;
  const uint4 q = *(const uint4*)&row[t * 16];
  const uint4 q2 = *(const uint4*)&row[t * 16 + 8];
  float s = bfl(q.x) + bfh(q.x) + bfl(q.y) + bfh(q.y) + bfl(q.z) + bfh(q.z)
          + bfl(q.w) + bfh(q.w) + bfl(q2.x) + bfh(q2.x) + bfl(q2.y) + bfh(q2.y)
          + bfl(q2.z) + bfh(q2.z) + bfl(q2.w) + bfh(q2.w);
  red[t] = s;
  __syncthreads();
  for (int st = 128; st > 0; st >>= 1) {
    if (t < st) red[t] += red[t + st];
    __syncthreads();
  }
  if (t == 0) x2sum[d] = red[0];
  const unsigned short pv = f2bf(red[0] * (P_UNIF * P_UNIF));
  const unsigned pk = (unsigned)pv | ((unsigned)pv << 16);
  uint4* dst = (uint4*)(Yt + (size_t)d * N4K);
  dst[t] = make_uint4(pk, pk, pk, pk);
  dst[t + 256] = make_uint4(pk, pk, pk, pk);
}

// ---------------- X2vt8[d][i] = fp8( X2t[d][i] * v[i] * 4096 ) ---------------
__global__ void k_x2v8(const unsigned short* __restrict__ X2t, const float* __restrict__ v,
                       unsigned char* __restrict__ X2vt8) {
  const int d = blockIdx.x, t = threadIdx.x;
  const int i0 = t * 16;
  const unsigned short* src = X2t + (size_t)d * N4K + i0;
  const uint4 a = *(const uint4*)src;
  const uint4 b = *(const uint4*)(src + 8);
  const float4 v0 = *(const float4*)&v[i0];
  const float4 v1 = *(const float4*)&v[i0 + 4];
  const float4 v2 = *(const float4*)&v[i0 + 8];
  const float4 v3 = *(const float4*)&v[i0 + 12];
  const float C = 4096.0f;
  unsigned w0 = f2fp8s(bfl(a.x) * v0.x * C) | (f2fp8s(bfh(a.x) * v0.y * C) << 8)
              | (f2fp8s(bfl(a.y) * v0.z * C) << 16) | (f2fp8s(bfh(a.y) * v0.w * C) << 24);
  unsigned w1 = f2fp8s(bfl(a.z) * v1.x * C) | (f2fp8s(bfh(a.z) * v1.y * C) << 8)
              | (f2fp8s(bfl(a.w) * v1.z * C) << 16) | (f2fp8s(bfh(a.w) * v1.w * C) << 24);
  unsigned w2 = f2fp8s(bfl(b.x) * v2.x * C) | (f2fp8s(bfh(b.x) * v2.y * C) << 8)
              | (f2fp8s(bfl(b.y) * v2.z * C) << 16) | (f2fp8s(bfh(b.y) * v2.w * C) << 24);
  unsigned w3 = f2fp8s(bfl(b.z) * v3.x * C) | (f2fp8s(bfh(b.z) * v3.y * C) << 8)
              | (f2fp8s(bfl(b.w) * v3.z * C) << 16) | (f2fp8s(bfh(b.w) * v3.w * C) << 24);
  *(uint4*)(X2vt8 + (size_t)d * N4K + i0) = make_uint4(w0, w1, w2, w3);
}

// ---------------- reduce 4 K-chunk partials of Y, apply u/4096, transpose ----
__global__ void k_redY(const float* __restrict__ Yp, const float* __restrict__ u,
                       unsigned short* __restrict__ Yt) {
  __shared__ float t[64][65];
  const int tid = threadIdx.x;
  const int tx = tid & 63, ty = tid >> 6;
  const int r0 = blockIdx.x * 64, c0 = blockIdx.y * 64;
#pragma unroll
  for (int k = 0; k < 16; k++) {
    const int r = ty * 16 + k;
    const size_t off = (size_t)(r0 + r) * 256 + c0 + tx;
    float s = 0.f;
#pragma unroll
    for (int z = 0; z < 4; z++) s += Yp[(size_t)z * (N4K * 256) + off];
    t[r][tx] = s;
  }
  __syncthreads();
  const float uu = u[r0 + tx] * P_UNIF;   // undo the 4096 scale in X2vt8
#pragma unroll
  for (int k = 0; k < 16; k++) {
    const int r = ty * 16 + k;
    Yt[(size_t)(c0 + r) * N4K + r0 + tx] = f2bf(t[tx][r] * uu);
  }
}

// ---------------- reduce 16 K-chunk partials of PT ---------------------------
__global__ void k_redPT(const float* __restrict__ Pp, unsigned short* __restrict__ PTb) {
  const int idx = blockIdx.x * 256 + threadIdx.x;
  float s = 0.f;
#pragma unroll
  for (int z = 0; z < 16; z++) s += Pp[z * 65536 + idx];
  PTb[idx] = f2bf(s);
}

// shift = sArg * mean(Z X2^T) - mean(ctE), rank-1: sum_i Z[i][d] = x1sum . PT[d][:]
__global__ void k_shift2(const unsigned short* __restrict__ PTb, const float* __restrict__ x1sum,
                         const float* __restrict__ x2sum, const float* __restrict__ ctsum,
                         const float* __restrict__ dm1, const float* __restrict__ dm2,
                         float* __restrict__ shift) {
  __shared__ float red[256];
  const int d = threadIdx.x;
  float zc = 0.f;
  const unsigned short* row = PTb + d * 256;
  for (int e = 0; e < 256; e++) zc += bfl((unsigned)row[e]) * x1sum[e];
  red[d] = zc * x2sum[d];
  __syncthreads();
  for (int st = 128; st > 0; st >>= 1) {
    if (d < st) red[d] += red[d + st];
    __syncthreads();
  }
  if (d == 0) {
    const float meanacc = red[0] * (1.0f / 16777216.0f);
    const float sArg = 40.0f / ((1.0f + *dm1) * (1.0f + *dm2));
    shift[0] = sArg * meanacc - ctsum[0] * (1.0f / N4K);
  }
}

// ---------------- fp8 Sinkhorn iteration (K8 L2-resident) --------------------
__global__ __launch_bounds__(512) void k_sink8(
    const unsigned char* __restrict__ K8, const float* __restrict__ vin,
    float* __restrict__ u, float* __restrict__ partials, int first, int last)
{
  __shared__ float vs[N4K];     // 16 KiB
  __shared__ float lut[256];
  __shared__ float us[16];
  const int tid = threadIdx.x;
  if (tid < 256) lut[tid] = fp8dec(tid);
  if (first) {
    for (int i = tid; i < N4K; i += 512) vs[i] = 1.0f;
  } else {
    float4* vl = (float4*)vs;
    const float4* vg = (const float4*)vin;
    vl[tid] = vg[tid];
    vl[tid + 512] = vg[tid + 512];
  }
  __syncthreads();
  const int wv = tid >> 6, lane = tid & 63;
  const int row0 = blockIdx.x * 16;

#if FP8_HW
#define DEC4(W, J, ACC) { \
    auto _lo = __builtin_amdgcn_cvt_pk_f32_fp8((int)(W), false); \
    auto _hi = __builtin_amdgcn_cvt_pk_f32_fp8((int)(W), true);  \
    ACC += _lo[0] * vs[(J)] + _lo[1] * vs[(J) + 1] + _hi[0] * vs[(J) + 2] + _hi[1] * vs[(J) + 3]; }
#else
#define DEC4(W, J, ACC) { \
    ACC += lut[(W) & 255] * vs[(J)] + lut[((W) >> 8) & 255] * vs[(J) + 1] \
         + lut[((W) >> 16) & 255] * vs[(J) + 2] + lut[(W) >> 24] * vs[(J) + 3]; }
#endif

  // phase A: u = p/(K v) for rows 2wv, 2wv+1
  {
    const uint4* rA = (const uint4*)(K8 + (size_t)(row0 + wv * 2) * N4K);
    const uint4* rB = (const uint4*)(K8 + (size_t)(row0 + wv * 2 + 1) * N4K);
    float accA = 0.f, accB = 0.f;
#pragma unroll
    for (int p = 0; p < 4; p++) {
      const int j0 = p * 1024 + lane * 16;
      const uint4 qa = rA[p * 64 + lane];
      const uint4 qb = rB[p * 64 + lane];
      DEC4(qa.x, j0, accA); DEC4(qa.y, j0 + 4, accA);
      DEC4(qa.z, j0 + 8, accA); DEC4(qa.w, j0 + 12, accA);
      DEC4(qb.x, j0, accB); DEC4(qb.y, j0 + 4, accB);
      DEC4(qb.z, j0 + 8, accB); DEC4(qb.w, j0 + 12, accB);
    }
#pragma unroll
    for (int off = 32; off; off >>= 1) {
      accA += __shfl_xor(accA, off);
      accB += __shfl_xor(accB, off);
    }
    if (lane == 0) {
      us[wv * 2] = P_UNIF / accA;
      us[wv * 2 + 1] = P_UNIF / accB;
    }
  }
  __syncthreads();
  float uu[16];
#pragma unroll
  for (int r = 0; r < 16; r++) uu[r] = us[r];
  // phase B: partial colsums of K^T u (8 cols/thread)
  {
    const int c0 = tid * 8;
    const unsigned char* base = K8 + (size_t)row0 * N4K + c0;
    float a0 = 0, a1 = 0, a2 = 0, a3 = 0, a4 = 0, a5 = 0, a6 = 0, a7 = 0;
#pragma unroll
    for (int r = 0; r < 16; r++) {
      const uint2 q = *(const uint2*)(base + (size_t)r * N4K);
      const float ur = uu[r];
#if FP8_HW
      auto l0 = __builtin_amdgcn_cvt_pk_f32_fp8((int)q.x, false);
      auto h0 = __builtin_amdgcn_cvt_pk_f32_fp8((int)q.x, true);
      auto l1 = __builtin_amdgcn_cvt_pk_f32_fp8((int)q.y, false);
      auto h1 = __builtin_amdgcn_cvt_pk_f32_fp8((int)q.y, true);
      a0 += ur * l0[0]; a1 += ur * l0[1]; a2 += ur * h0[0]; a3 += ur * h0[1];
      a4 += ur * l1[0]; a5 += ur * l1[1]; a6 += ur * h1[0]; a7 += ur * h1[1];
#else
      a0 += ur * lut[q.x & 255]; a1 += ur * lut[(q.x >> 8) & 255];
      a2 += ur * lut[(q.x >> 16) & 255]; a3 += ur * lut[q.x >> 24];
      a4 += ur * lut[q.y & 255]; a5 += ur * lut[(q.y >> 8) & 255];
      a6 += ur * lut[(q.y >> 16) & 255]; a7 += ur * lut[q.y >> 24];
#endif
    }
    float* pp = partials + (size_t)blockIdx.x * N4K + c0;
    *(float4*)pp = make_float4(a0, a1, a2, a3);
    *(float4*)(pp + 4) = make_float4(a4, a5, a6, a7);
  }
  if (last && tid < 16) u[row0 + tid] = us[tid];
}

// v_j = q / sum_{b<256} partials[b][j].  grid 128 x 256; block covers 32 cols.
__global__ void k_sinkfin(const float* __restrict__ partials, float* __restrict__ v) {
  __shared__ float red[8][32];
  const int tid = threadIdx.x;
  const int c = (blockIdx.x << 5) + (tid & 31);
  const int s = tid >> 5;                     // 0..7
  float acc = 0.f;
  const float* p = partials + (size_t)s * 32 * N4K + c;
#pragma unroll 8
  for (int b = 0; b < 32; b++) acc += p[(size_t)b * N4K];
  red[s][tid & 31] = acc;
  __syncthreads();
  if (s == 0) {
    float t = red[0][tid] + red[1][tid] + red[2][tid] + red[3][tid]
            + red[4][tid] + red[5][tid] + red[6][tid] + red[7][tid];
    v[c] = P_UNIF / t;
  }
}

// ---------------- loss = -sum log(u_i K8_ii v_i + 1e-10) ---------------------
__global__ void k_loss(const unsigned char* __restrict__ K8, const float* __restrict__ u,
                       const float* __restrict__ v, float* __restrict__ out) {
  const int tid = threadIdx.x;
  float acc = 0.f;
  for (int i = tid; i < N4K; i += 256) {
    const float d = u[i] * fp8dec(K8[(size_t)i * (N4K + 1)]) * v[i];
    acc += logf(d + 1e-10f);
  }
  __shared__ float red[256];
  red[tid] = acc;
  __syncthreads();
  for (int st = 128; st > 0; st >>= 1) {
    if (tid < st) red[tid] += red[tid + st];
    __syncthreads();
  }
  if (tid == 0) out[0] = -red[0];
}

// ============================================================================
extern "C" void kernel_launch(void* const* d_in, const int* in_sizes, int n_in,
                              void* d_out, int out_size, void* d_ws, size_t ws_size,
                              hipStream_t stream) {
  const float* f1 = (const float*)d_in[0];
  const float* f2 = (const float*)d_in[1];
  float* out = (float*)d_out;

  char* w = (char*)d_ws;
  const size_t NN = (size_t)N4K * N4K;
  unsigned short* X1 = (unsigned short*)w;   w += (size_t)N4K * DFEAT * 2;
  unsigned short* X2 = (unsigned short*)w;   w += (size_t)N4K * DFEAT * 2;
  unsigned short* X1t = (unsigned short*)w;  w += (size_t)N4K * DFEAT * 2;
  unsigned short* X2t = (unsigned short*)w;  w += (size_t)N4K * DFEAT * 2;
  unsigned char* X2vt8 = (unsigned char*)w;  w += (size_t)N4K * DFEAT;
  unsigned short* Zb = (unsigned short*)w;   w += (size_t)N4K * DFEAT * 2;
  unsigned short* Yt = (unsigned short*)w;   w += (size_t)N4K * DFEAT * 2;
  unsigned short* PTb = (unsigned short*)w;  w += (size_t)DFEAT * DFEAT * 2;
  unsigned char* K8 = (unsigned char*)w;     w += NN;        // fp8 K, 16.8 MB
  float* Yp = (float*)w;    w += (size_t)4 * N4K * DFEAT * 4;    // 16 MB
  float* Pp = (float*)w;    w += (size_t)16 * DFEAT * DFEAT * 4; // 4 MB
  float* spart = (float*)w; w += (size_t)256 * N4K * 4;          // 4 MB
  float* stats = (float*)w; w += (size_t)16704 * 4;
  float* uvec = (float*)w;  w += N4K * 4;
  float* vvec = (float*)w;  w += N4K * 4;
  float* ctE = (float*)w;   w += N4K * 4;
  float* x2sum = (float*)w; w += 256 * 4;
  float* x1sum = (float*)w; w += 256 * 4;

  float* psum2 = stats;
  float* psq2 = stats + 4096;
  float* psumD = stats + 8192;
  float* psqD = stats + 12288;
  float* dmax1 = stats + 16384;
  float* dmax2 = stats + 16385;
  float* ctsum = stats + 16386;
  float* shiftv = stats + 16387;

  const dim3 b256(256);

  k_normalize<<<1024, b256, 0, stream>>>(f1, X1);
  k_normalize<<<1024, b256, 0, stream>>>(f2, X2);
  k_transpose<<<dim3(4, 64), b256, 0, stream>>>(X1, X1t, N4K, DFEAT);
  k_transpose<<<dim3(4, 64), b256, 0, stream>>>(X2, X2t, N4K, DFEAT);
  k_rsum<<<256, b256, 0, stream>>>(X1t, x1sum);
  k_zerof<<<66, b256, 0, stream>>>(stats, 16704);

  // Gram stats (mode 4): G1 -> dmax1; G2 -> colsums + dmax2
  k_gemm_bt<<<dim3(32, 32, 1), b256, 0, stream>>>(X1, X1, DFEAT, DFEAT, nullptr, nullptr,
                                                  0, 4, nullptr, nullptr, nullptr,
                                                  psumD, psqD, dmax1, nullptr, nullptr);
  k_gemm_bt<<<dim3(32, 32, 1), b256, 0, stream>>>(X2, X2, DFEAT, DFEAT, nullptr, nullptr,
                                                  0, 4, nullptr, nullptr, nullptr,
                                                  psum2, psq2, dmax2, nullptr, nullptr);
  k_ctfinal<<<16, b256, 0, stream>>>(psum2, psq2, dmax1, dmax2, ctE, ctsum);

  for (int it = 0; it < 5; it++) {
    if (it == 0) {
      k_yt0<<<256, b256, 0, stream>>>(X2t, Yt, x2sum);
    } else {
      // T = u (.) K8 (.) v implicitly: Y = diag(u/4096) K8 (diag(4096 v) X2), fp8 MFMA
      k_x2v8<<<256, b256, 0, stream>>>(X2t, vvec, X2vt8);
      k_gemm_bt<<<dim3(2, 32, 4), b256, 0, stream>>>((const unsigned short*)K8,
                                                     (const unsigned short*)X2vt8,
                                                     N4K, 1024, nullptr, Yp,
                                                     DFEAT, 5, nullptr, nullptr, nullptr,
                                                     nullptr, nullptr, nullptr, nullptr, nullptr);
      k_redY<<<dim3(64, 4), b256, 0, stream>>>(Yp, uvec, Yt);
    }
    // PT = Y^T X1 (K-split 16)
    k_gemm_bt<<<dim3(2, 2, 16), b256, 0, stream>>>(Yt, X1t, N4K, 256, nullptr, Pp,
                                                   DFEAT, 3, nullptr, nullptr, nullptr,
                                                   nullptr, nullptr, nullptr, nullptr, nullptr);
    k_redPT<<<256, b256, 0, stream>>>(Pp, PTb);
    // Z = X1 P
    k_gemm_bt<<<dim3(2, 32, 1), b256, 0, stream>>>(X1, PTb, DFEAT, DFEAT, Zb, nullptr,
                                                   DFEAT, 0, nullptr, nullptr, nullptr,
                                                   nullptr, nullptr, nullptr, nullptr, nullptr);
    // shift = sArg*mean(Z X2^T) - mean(ctE), from PTb rank-1 identity
    k_shift2<<<1, b256, 0, stream>>>(PTb, x1sum, x2sum, ctsum, dmax1, dmax2, shiftv);
    // K8 = fp8( exp(sArg * Z X2^T - ctE_j - shift) )
    k_gemm_bt<<<dim3(32, 32, 1), b256, 0, stream>>>(Zb, X2, DFEAT, DFEAT, nullptr, nullptr,
                                                    N4K, 2, ctE, dmax1, dmax2,
                                                    nullptr, nullptr, nullptr, K8, shiftv);
    // Sinkhorn: 20 x { u = p/(K v) ; v = q/(K^T u) }, v0 = 1, on fp8 K
    for (int s = 0; s < 20; s++) {
      k_sink8<<<256, dim3(512), 0, stream>>>(K8, vvec, uvec, spart,
                                             s == 0 ? 1 : 0, s == 19 ? 1 : 0);
      k_sinkfin<<<128, b256, 0, stream>>>(spart, vvec);
    }
  }
  k_loss<<<1, b256, 0, stream>>>(K8, uvec, vvec, out);
}